// Round 6
// baseline (283.294 us; speedup 1.0000x reference)
//
#include <hip/hip_runtime.h>
#include <math.h>

typedef __attribute__((ext_vector_type(8))) short bf16x8;
typedef __attribute__((ext_vector_type(4))) float f32x4;
#define MFMA16(a, b, c) __builtin_amdgcn_mfma_f32_16x16x32_bf16(a, b, c, 0, 0, 0)

union U8 { bf16x8 v; int i4[4]; };

__device__ __forceinline__ unsigned short f2bf(float x) {
    unsigned u = __builtin_bit_cast(unsigned, x);
    unsigned r = (u + 0x7fffu + ((u >> 16) & 1u)) >> 16;   // RNE
    return (unsigned short)r;
}
// packed RNE f32x2 -> bf16x2 (dst.lo = cvt(src0), dst.hi = cvt(src1))
__device__ __forceinline__ unsigned cvtpk(float lo, float hi) {
    unsigned r;
    asm("v_cvt_pk_bf16_f32 %0, %1, %2" : "=v"(r) : "v"(lo), "v"(hi));
    return r;
}

// conv1 K-permutation sigma (same on A and B, cancels):
__device__ __forceinline__ int koff_of(int kidx) {
    int grp = kidx >> 3, e = kidx & 7;
    if (grp < 9)  return grp * 9 + e;
    if (grp == 9) return e * 9 + 8;
    if (grp == 10) return (e == 0) ? 80 : -1;
    return -1;
}

#define CAPS_BYTES 37748736
#define A1F_ELEMS  24576
#define W3F_ELEMS  82944   // 81 taps * 2 m * 64 lanes * 8 e

// ---------------------------------------------------------------------------
// K0: pack conv weights into MFMA fragment layout (bf16)
// ---------------------------------------------------------------------------
__global__ void k_prep(const float* __restrict__ c1w,  // [256,1,9,9]
                       const float* __restrict__ pw,   // [32,32,1,9,9]
                       unsigned short* __restrict__ w1f,
                       unsigned short* __restrict__ w3f)
{
    int idx = blockIdx.x * 256 + threadIdx.x;
    if (idx < A1F_ELEMS) {
        int e = idx & 7, lane = (idx >> 3) & 63, f = idx >> 9;
        int k3 = f % 3, m = (f / 3) & 1, d = f / 6;
        int ch = (lane & 15) + m * 16;
        int kidx = k3 * 32 + ((lane >> 4) << 3) + e;
        int ko = koff_of(kidx);
        w1f[idx] = f2bf(ko >= 0 ? c1w[(ch * 8 + d) * 81 + ko] : 0.f);
    } else if (idx < A1F_ELEMS + W3F_ELEMS) {
        int j = idx - A1F_ELEMS;
        int e = j & 7, lane = (j >> 3) & 63, f = j >> 9;
        int m = f & 1, tap = f >> 1;
        int oc = (lane & 15) + m * 16;
        int i = ((lane >> 4) << 3) + e;
        w3f[j] = f2bf(pw[oc * 2592 + i * 81 + tap]);
    }
}

// ---------------------------------------------------------------------------
// K1: fused conv1 + prim conv. One block = one (b,d) slice. 4 blocks/CU.
// interm: [pos 400][ch 40-stride] u16 linear (no swizzle).
// Phase 2: wave w owns rows ky={2w,2w+1} (+ row-8 leftovers), kx unrolled ->
// LDS addresses are base VGPR + compile-time offset immediates.
// ---------------------------------------------------------------------------
__global__ __launch_bounds__(256, 4) void k_conv(
    const float* __restrict__ x,    // [1024,1,28,28]
    const float* __restrict__ c1b,  // [256]
    const float* __restrict__ pb,   // [32]
    const unsigned short* __restrict__ w1f,
    const unsigned short* __restrict__ w3f,
    float* __restrict__ caps)       // [1024,8,1152]
{
    __shared__ __align__(16) unsigned short img[800];
    __shared__ __align__(16) unsigned short imgs[800];          // shifted by 1
    __shared__ __align__(128) unsigned short interm[400 * 40];  // 32000 B

    const int t = threadIdx.x;
    const int lane = t & 63, w = t >> 6;
    const int g = lane >> 4, col = lane & 15;
    const int b = blockIdx.x >> 3, d = blockIdx.x & 7;

    for (int idx = t; idx < 784; idx += 256) {
        unsigned short v = f2bf(x[b * 784 + idx]);
        img[idx] = v;
        if (idx > 0) imgs[idx - 1] = v;
    }
    __syncthreads();

    // =================== phase 1: conv1 ===================
    {
        bf16x8 a1[2][3];
        const bf16x8* w1p = (const bf16x8*)w1f;
#pragma unroll
        for (int m = 0; m < 2; ++m)
#pragma unroll
            for (int k3 = 0; k3 < 3; ++k3)
                a1[m][k3] = w1p[((d * 2 + m) * 3 + k3) * 64 + lane];

        float bias[2][4];
#pragma unroll
        for (int m = 0; m < 2; ++m)
#pragma unroll
            for (int r = 0; r < 4; ++r)
                bias[m][r] = c1b[(m * 16 + g * 4 + r) * 8 + d];

        for (int q = w; q < 25; q += 4) {
            int p = q * 16 + col;
            int py = p / 20, px = p - py * 20;
            int base = py * 28 + px;
            const unsigned short* rbase = (base & 1) ? &imgs[base - 1] : &img[base];

            bf16x8 bfrag[3];
#pragma unroll
            for (int k3 = 0; k3 < 2; ++k3) {
                int grp = k3 * 4 + g;
                U8 u8;
#pragma unroll
                for (int qq = 0; qq < 4; ++qq)
                    u8.i4[qq] = *(const int*)(rbase + grp * 28 + 2 * qq);
                bfrag[k3] = u8.v;
            }
            {
                U8 u8;
                if (g == 0) {
#pragma unroll
                    for (int qq = 0; qq < 4; ++qq)
                        u8.i4[qq] = *(const int*)(rbase + 8 * 28 + 2 * qq);
                } else if (g == 1) {
#pragma unroll
                    for (int e = 0; e < 8; ++e)
                        u8.v[e] = (short)img[base + e * 28 + 8];
                } else if (g == 2) {
                    u8.i4[0] = u8.i4[1] = u8.i4[2] = u8.i4[3] = 0;
                    u8.v[0] = (short)img[base + 8 * 28 + 8];
                } else {
                    u8.i4[0] = u8.i4[1] = u8.i4[2] = u8.i4[3] = 0;
                }
                bfrag[2] = u8.v;
            }

            f32x4 acc0 = {0.f, 0.f, 0.f, 0.f};
            f32x4 acc1 = {0.f, 0.f, 0.f, 0.f};
#pragma unroll
            for (int k3 = 0; k3 < 3; ++k3) {
                acc0 = MFMA16(a1[0][k3], bfrag[k3], acc0);
                acc1 = MFMA16(a1[1][k3], bfrag[k3], acc1);
            }
            float r0[4], r1[4];
#pragma unroll
            for (int r = 0; r < 4; ++r) {
                r0[r] = fmaxf(acc0[r] + bias[0][r], 0.f);
                r1[r] = fmaxf(acc1[r] + bias[1][r], 0.f);
            }
            *(uint2*)(&interm[p * 40 + g * 4])      = make_uint2(cvtpk(r0[0], r0[1]), cvtpk(r0[2], r0[3]));
            *(uint2*)(&interm[p * 40 + 16 + g * 4]) = make_uint2(cvtpk(r1[0], r1[1]), cvtpk(r1[2], r1[3]));
        }
    }
    __syncthreads();

    // =================== phase 2: prim conv, row-split by wave ===================
    f32x4 acc[2][3];
#pragma unroll
    for (int m = 0; m < 2; ++m)
#pragma unroll
        for (int nt = 0; nt < 3; ++nt)
            acc[m][nt] = (f32x4){0.f, 0.f, 0.f, 0.f};
    {
        int abase[3];   // byte base per nt: pos0*80 + g*16
#pragma unroll
        for (int nt = 0; nt < 3; ++nt) {
            int p2 = nt * 16 + col;
            int xw = p2 / 6, yh = p2 - xw * 6;
            int pos0 = (p2 < 36) ? (yh * 40 + xw * 2) : 0;
            abase[nt] = pos0 * 80 + g * 16;
        }
        const bf16x8* w3p = (const bf16x8*)w3f;
        const char* ib = (const char*)interm;

        for (int rr = 0; rr < 2; ++rr) {
            const int ky = 2 * w + rr;
            const bf16x8* wrow = w3p + (ky * 9) * 128;
            const char* B0 = ib + abase[0] + ky * 1600;
            const char* B1 = ib + abase[1] + ky * 1600;
            const char* B2 = ib + abase[2] + ky * 1600;
#pragma unroll
            for (int kx = 0; kx < 9; ++kx) {
                bf16x8 a0  = wrow[kx * 128 + lane];
                bf16x8 a1v = wrow[kx * 128 + 64 + lane];
                bf16x8 b0 = *(const bf16x8*)(B0 + kx * 80);
                bf16x8 b1 = *(const bf16x8*)(B1 + kx * 80);
                bf16x8 b2 = *(const bf16x8*)(B2 + kx * 80);
                acc[0][0] = MFMA16(a0, b0, acc[0][0]);
                acc[1][0] = MFMA16(a1v, b0, acc[1][0]);
                acc[0][1] = MFMA16(a0, b1, acc[0][1]);
                acc[1][1] = MFMA16(a1v, b1, acc[1][1]);
                acc[0][2] = MFMA16(a0, b2, acc[0][2]);
                acc[1][2] = MFMA16(a1v, b2, acc[1][2]);
            }
        }
        // row 8 leftovers: w0:{0,1} w1:{2,3} w2:{4,5} w3:{6,7,8}
        {
            const bf16x8* wrow = w3p + 72 * 128;
            const char* B0 = ib + abase[0] + 12800;
            const char* B1 = ib + abase[1] + 12800;
            const char* B2 = ib + abase[2] + 12800;
            int kx0 = 2 * w;
            int nkx = (w == 3) ? 3 : 2;
#pragma unroll 3
            for (int q = 0; q < nkx; ++q) {
                int kx = kx0 + q;
                bf16x8 a0  = wrow[kx * 128 + lane];
                bf16x8 a1v = wrow[kx * 128 + 64 + lane];
                bf16x8 b0 = *(const bf16x8*)(B0 + kx * 80);
                bf16x8 b1 = *(const bf16x8*)(B1 + kx * 80);
                bf16x8 b2 = *(const bf16x8*)(B2 + kx * 80);
                acc[0][0] = MFMA16(a0, b0, acc[0][0]);
                acc[1][0] = MFMA16(a1v, b0, acc[1][0]);
                acc[0][1] = MFMA16(a0, b1, acc[0][1]);
                acc[1][1] = MFMA16(a1v, b1, acc[1][1]);
                acc[0][2] = MFMA16(a0, b2, acc[0][2]);
                acc[1][2] = MFMA16(a1v, b2, acc[1][2]);
            }
        }
    }
    __syncthreads();
    // ---- cross-wave reduction (f32x4 overlay on interm) ----
    f32x4* rp = (f32x4*)&interm[0];
    {
#pragma unroll
        for (int m = 0; m < 2; ++m)
#pragma unroll
            for (int nt = 0; nt < 3; ++nt)
                rp[(w * 6 + m * 3 + nt) * 64 + lane] = acc[m][nt];
    }
    __syncthreads();
    for (int idx = t; idx < 384; idx += 256) {
        int tile = idx >> 6, ls = idx & 63;
        f32x4 s = rp[tile * 64 + ls];
#pragma unroll
        for (int ww = 1; ww < 4; ++ww)
            s += rp[(ww * 6 + tile) * 64 + ls];
        int m = tile / 3, nt = tile - m * 3;
        int p2 = nt * 16 + (ls & 15);
        if (p2 < 36) {
            int gr = ls >> 4;
#pragma unroll
            for (int r = 0; r < 4; ++r) {
                int oc = m * 16 + gr * 4 + r;
                caps[(b * 8 + d) * 1152 + oc * 36 + p2] = fmaxf(s[r] + pb[oc], 0.f);
            }
        }
    }
}

// ---------------------------------------------------------------------------
// K2: routing. TWO batch elements per block (1024 threads, 16 waves).
// u,c bf16 in LDS; stage C via MFMA; routing logits in registers.
// ---------------------------------------------------------------------------
#define USB 1160
#define CSB 1160

__global__ __launch_bounds__(1024) void k_route(
    const float* __restrict__ caps,  // [1024,8,1152]
    const float* __restrict__ W,     // [1152,8,16]
    const float* __restrict__ Wb,    // [1152,16]
    const float* __restrict__ ow,    // [10,10,16,1]
    const float* __restrict__ ob,    // [10]
    float* __restrict__ out)         // [1024,10]
{
    __shared__ __align__(16) unsigned short u_bf[2 * 16 * USB];  // 74,240 B
    __shared__ __align__(16) unsigned short c_bf[2 * 10 * CSB];  // 46,400 B
    __shared__ __align__(16) float sred[18 * 256];               // 18,432 B
    __shared__ __align__(16) float vv[2 * 192];
    __shared__ float ss[2 * 160];
    __shared__ float red2[32];

    const int t = threadIdx.x;
    const int lane = t & 63, wv = t >> 6;
    const int g = lane >> 4, col = lane & 15;
    const int b0 = blockIdx.x * 2;

    // main pair: slots (2t, 2t+1); extra pair for t<128: b1, n 896+2t
    const int mbs = (t >= 576);
    const int mn0 = 2 * t - mbs * 1152;
    const bool xact = (t < 128);
    const int xn0 = 896 + 2 * t;

    // ---- stage A: u[bs][f][n] -> bf16 ----
    {
        const int nl = t >> 2, fq = t & 3;
#pragma unroll
        for (int it = 0; it < 9; ++it) {
            int row = it * 256 + nl;
            int bs = row >= 1152;
            int n = row - bs * 1152;
            const float* capb = caps + (size_t)(b0 + bs) * 9216;
            float cv[8];
#pragma unroll
            for (int e = 0; e < 8; ++e) cv[e] = capb[e * 1152 + n];
            float4 a4 = ((const float4*)(Wb + n * 16))[fq];
#pragma unroll
            for (int e = 0; e < 8; ++e) {
                float4 w4 = ((const float4*)(W + n * 128 + e * 16))[fq];
                a4.x += cv[e] * w4.x; a4.y += cv[e] * w4.y;
                a4.z += cv[e] * w4.z; a4.w += cv[e] * w4.w;
            }
            unsigned short* ub = u_bf + (size_t)bs * 16 * USB;
            ub[(fq * 4 + 0) * USB + n] = f2bf(a4.x);
            ub[(fq * 4 + 1) * USB + n] = f2bf(a4.y);
            ub[(fq * 4 + 2) * USB + n] = f2bf(a4.z);
            ub[(fq * 4 + 3) * USB + n] = f2bf(a4.w);
        }
    }
    float breg[2][10], xreg[2][10];
#pragma unroll
    for (int s = 0; s < 2; ++s)
#pragma unroll
        for (int jj = 0; jj < 10; ++jj) { breg[s][jj] = 0.f; xreg[s][jj] = 0.f; }
    __syncthreads();

    const int jrow = (col < 10) ? col : 9;
    // stage C chunk for this wave: chunk wv, plus chunk 16+wv for wv<2
    for (int iter = 0; iter < 3; ++iter) {
        // ---- stage B: thread-local softmax -> c_bf ----
        {
            float cv2[2][10];
#pragma unroll
            for (int s = 0; s < 2; ++s) {
                float m = breg[s][0];
#pragma unroll
                for (int jj = 1; jj < 10; ++jj) m = fmaxf(m, breg[s][jj]);
                float sum = 0.f;
#pragma unroll
                for (int jj = 0; jj < 10; ++jj) { cv2[s][jj] = __expf(breg[s][jj] - m); sum += cv2[s][jj]; }
                float inv = 1.f / sum;
#pragma unroll
                for (int jj = 0; jj < 10; ++jj) cv2[s][jj] *= inv;
            }
            unsigned short* cb = c_bf + (size_t)mbs * 10 * CSB;
#pragma unroll
            for (int jj = 0; jj < 10; ++jj)
                *(unsigned*)(&cb[jj * CSB + mn0]) = cvtpk(cv2[0][jj], cv2[1][jj]);
            if (xact) {
                float xv[2][10];
#pragma unroll
                for (int s = 0; s < 2; ++s) {
                    float m = xreg[s][0];
#pragma unroll
                    for (int jj = 1; jj < 10; ++jj) m = fmaxf(m, xreg[s][jj]);
                    float sum = 0.f;
#pragma unroll
                    for (int jj = 0; jj < 10; ++jj) { xv[s][jj] = __expf(xreg[s][jj] - m); sum += xv[s][jj]; }
                    float inv = 1.f / sum;
#pragma unroll
                    for (int jj = 0; jj < 10; ++jj) xv[s][jj] *= inv;
                }
                unsigned short* cb1 = c_bf + (size_t)10 * CSB;
#pragma unroll
                for (int jj = 0; jj < 10; ++jj)
                    *(unsigned*)(&cb1[jj * CSB + xn0]) = cvtpk(xv[0][jj], xv[1][jj]);
            }
        }
        __syncthreads();
        // ---- stage C: s[bs][j][f] via MFMA over 18 K-chunks of 128 ----
        {
            int c0 = wv;
            {
                int bs = c0 >= 9;
                int nb = (c0 - bs * 9) * 128;
                const unsigned short* cb = c_bf + (size_t)bs * 10 * CSB;
                const unsigned short* ub = u_bf + (size_t)bs * 16 * USB;
                f32x4 sp = {0.f, 0.f, 0.f, 0.f};
#pragma unroll
                for (int mf = 0; mf < 4; ++mf) {
                    int nk = nb + mf * 32 + g * 8;
                    bf16x8 af = *(const bf16x8*)(&cb[jrow * CSB + nk]);
                    bf16x8 bf = *(const bf16x8*)(&ub[col * USB + nk]);
                    sp = MFMA16(af, bf, sp);
                }
                *(f32x4*)(&sred[c0 * 256 + lane * 4]) = sp;
            }
            if (wv < 2) {
                int c1 = 16 + wv;
                int bs = 1;
                int nb = (c1 - 9) * 128;
                const unsigned short* cb = c_bf + (size_t)bs * 10 * CSB;
                const unsigned short* ub = u_bf + (size_t)bs * 16 * USB;
                f32x4 sp = {0.f, 0.f, 0.f, 0.f};
#pragma unroll
                for (int mf = 0; mf < 4; ++mf) {
                    int nk = nb + mf * 32 + g * 8;
                    bf16x8 af = *(const bf16x8*)(&cb[jrow * CSB + nk]);
                    bf16x8 bf = *(const bf16x8*)(&ub[col * USB + nk]);
                    sp = MFMA16(af, bf, sp);
                }
                *(f32x4*)(&sred[c1 * 256 + lane * 4]) = sp;
            }
        }
        __syncthreads();
        // ---- reduce 9 chunk-partials per bs -> ss ----
        if (t < 320) {
            int bs = t >= 160;
            int r = t - bs * 160;
            int j = r >> 4, f = r & 15;
            int li = ((j >> 2) * 16 + f) * 4 + (j & 3);
            float s = 0.f;
#pragma unroll
            for (int cc = 0; cc < 9; ++cc) s += sred[(bs * 9 + cc) * 256 + li];
            ss[bs * 160 + j * 16 + f] = s;
        }
        __syncthreads();
        // ---- squash -> vv[bs][f][j] ----
        if (t < 32) {
            int bs = t >= 16, f = t & 15;
            float sv[10], l2 = 0.f, l1 = 0.f;
#pragma unroll
            for (int jj = 0; jj < 10; ++jj) {
                sv[jj] = ss[bs * 160 + jj * 16 + f];
                l2 += sv[jj] * sv[jj]; l1 += fabsf(sv[jj]);
            }
            l2 = sqrtf(l2);
            float scale = l2 / (1.f + l2) / l1;
#pragma unroll
            for (int jj = 0; jj < 10; ++jj) vv[bs * 192 + f * 12 + jj] = sv[jj] * scale;
        }
        __syncthreads();
        // ---- stage E: breg += u^T v ----
        if (iter < 2) {
            {
                const unsigned short* ub = u_bf + (size_t)mbs * 16 * USB;
                const float* vb = vv + mbs * 192;
#pragma unroll
                for (int f = 0; f < 16; ++f) {
                    unsigned pair = *(const unsigned*)(&ub[f * USB + mn0]);
                    float ux = __builtin_bit_cast(float, pair << 16);
                    float uy = __builtin_bit_cast(float, pair & 0xffff0000u);
#pragma unroll
                    for (int jj = 0; jj < 10; ++jj) {
                        float vj = vb[f * 12 + jj];
                        breg[0][jj] += ux * vj;
                        breg[1][jj] += uy * vj;
                    }
                }
            }
            if (xact) {
                const unsigned short* ub = u_bf + (size_t)16 * USB;
                const float* vb = vv + 192;
#pragma unroll
                for (int f = 0; f < 16; ++f) {
                    unsigned pair = *(const unsigned*)(&ub[f * USB + xn0]);
                    float ux = __builtin_bit_cast(float, pair << 16);
                    float uy = __builtin_bit_cast(float, pair & 0xffff0000u);
#pragma unroll
                    for (int jj = 0; jj < 10; ++jj) {
                        float vj = vb[f * 12 + jj];
                        xreg[0][jj] += ux * vj;
                        xreg[1][jj] += uy * vj;
                    }
                }
            }
        }
        __syncthreads();
    }

    // ---- output head + softmax (both b's) ----
    if (t < 20) {
        int bs = t >= 10, o = t - bs * 10;
        const float* vb = vv + bs * 192;
        float l = ob[o];
#pragma unroll
        for (int i2 = 0; i2 < 10; ++i2)
#pragma unroll
            for (int ff = 0; ff < 16; ++ff)
                l += vb[ff * 12 + i2] * ow[o * 160 + i2 * 16 + ff];
        red2[bs * 16 + o] = l;
    }
    __syncthreads();
    if (t < 2) {
        float m = -1e30f;
        for (int o = 0; o < 10; ++o) m = fmaxf(m, red2[t * 16 + o]);
        float sum = 0.f; float e[10];
        for (int o = 0; o < 10; ++o) { e[o] = __expf(red2[t * 16 + o] - m); sum += e[o]; }
        float inv = 1.f / sum;
        for (int o = 0; o < 10; ++o) out[(b0 + t) * 10 + o] = e[o] * inv;
    }
}

extern "C" void kernel_launch(void* const* d_in, const int* in_sizes, int n_in,
                              void* d_out, int out_size, void* d_ws, size_t ws_size,
                              hipStream_t stream) {
    const float* x     = (const float*)d_in[0];
    const float* c1w   = (const float*)d_in[1];
    const float* c1b   = (const float*)d_in[2];
    const float* pw    = (const float*)d_in[3];
    const float* pb    = (const float*)d_in[4];
    const float* digW  = (const float*)d_in[5];
    const float* digWb = (const float*)d_in[6];
    const float* outw  = (const float*)d_in[7];
    const float* outb  = (const float*)d_in[8];
    float* out = (float*)d_out;

    float* caps = (float*)d_ws;
    unsigned short* w1f = (unsigned short*)((char*)d_ws + CAPS_BYTES);
    unsigned short* w3f = w1f + A1F_ELEMS;

    k_prep<<<dim3(420), dim3(256), 0, stream>>>(c1w, pw, w1f, w3f);
    k_conv<<<dim3(8192), dim3(256), 0, stream>>>(x, c1b, pb, w1f, w3f, caps);
    k_route<<<dim3(512), dim3(1024), 0, stream>>>(caps, digW, digWb, outw, outb, out);
}

// Round 7
// 181.492 us; speedup vs baseline: 1.5609x; 1.5609x over previous
//
#include <hip/hip_runtime.h>
#include <math.h>

typedef __attribute__((ext_vector_type(8))) short bf16x8;
typedef __attribute__((ext_vector_type(4))) float f32x4;
#define MFMA16(a, b, c) __builtin_amdgcn_mfma_f32_16x16x32_bf16(a, b, c, 0, 0, 0)

union U8 { bf16x8 v; int i4[4]; };

__device__ __forceinline__ unsigned short f2bf(float x) {
    unsigned u = __builtin_bit_cast(unsigned, x);
    unsigned r = (u + 0x7fffu + ((u >> 16) & 1u)) >> 16;   // RNE
    return (unsigned short)r;
}
// packed RNE f32x2 -> bf16x2 (dst.lo = cvt(src0), dst.hi = cvt(src1))
__device__ __forceinline__ unsigned cvtpk(float lo, float hi) {
    unsigned r;
    asm("v_cvt_pk_bf16_f32 %0, %1, %2" : "=v"(r) : "v"(lo), "v"(hi));
    return r;
}

// conv1 K-permutation sigma (same on A and B, cancels):
__device__ __forceinline__ int koff_of(int kidx) {
    int grp = kidx >> 3, e = kidx & 7;
    if (grp < 9)  return grp * 9 + e;
    if (grp == 9) return e * 9 + 8;
    if (grp == 10) return (e == 0) ? 80 : -1;
    return -1;
}

#define CAPS_BYTES 37748736
#define A1F_ELEMS  24576
#define W3F_ELEMS  82944   // 81 taps * 2 m * 64 lanes * 8 e

// ---------------------------------------------------------------------------
// K0: pack conv weights into MFMA fragment layout (bf16)
// ---------------------------------------------------------------------------
__global__ void k_prep(const float* __restrict__ c1w,  // [256,1,9,9]
                       const float* __restrict__ pw,   // [32,32,1,9,9]
                       unsigned short* __restrict__ w1f,
                       unsigned short* __restrict__ w3f)
{
    int idx = blockIdx.x * 256 + threadIdx.x;
    if (idx < A1F_ELEMS) {
        int e = idx & 7, lane = (idx >> 3) & 63, f = idx >> 9;
        int k3 = f % 3, m = (f / 3) & 1, d = f / 6;
        int ch = (lane & 15) + m * 16;
        int kidx = k3 * 32 + ((lane >> 4) << 3) + e;
        int ko = koff_of(kidx);
        w1f[idx] = f2bf(ko >= 0 ? c1w[(ch * 8 + d) * 81 + ko] : 0.f);
    } else if (idx < A1F_ELEMS + W3F_ELEMS) {
        int j = idx - A1F_ELEMS;
        int e = j & 7, lane = (j >> 3) & 63, f = j >> 9;
        int m = f & 1, tap = f >> 1;
        int oc = (lane & 15) + m * 16;
        int i = ((lane >> 4) << 3) + e;
        w3f[j] = f2bf(pw[oc * 2592 + i * 81 + tap]);
    }
}

// ---------------------------------------------------------------------------
// K1: fused conv1 + prim conv. One block = one (b,d) slice. 4 blocks/CU.
// interm: [pos 400][ch 40-stride] u16 linear.
// Phase 2: wave w owns rows ky={2w,2w+1} (+ row-8 leftovers), kx unrolled ->
// LDS addresses are base VGPR + compile-time offset immediates.
// ---------------------------------------------------------------------------
__global__ __launch_bounds__(256, 4) void k_conv(
    const float* __restrict__ x,    // [1024,1,28,28]
    const float* __restrict__ c1b,  // [256]
    const float* __restrict__ pb,   // [32]
    const unsigned short* __restrict__ w1f,
    const unsigned short* __restrict__ w3f,
    float* __restrict__ caps)       // [1024,8,1152]
{
    __shared__ __align__(16) unsigned short img[800];
    __shared__ __align__(16) unsigned short imgs[800];          // shifted by 1
    __shared__ __align__(128) unsigned short interm[400 * 40];  // 32000 B

    const int t = threadIdx.x;
    const int lane = t & 63, w = t >> 6;
    const int g = lane >> 4, col = lane & 15;
    const int b = blockIdx.x >> 3, d = blockIdx.x & 7;

    for (int idx = t; idx < 784; idx += 256) {
        unsigned short v = f2bf(x[b * 784 + idx]);
        img[idx] = v;
        if (idx > 0) imgs[idx - 1] = v;
    }
    __syncthreads();

    // =================== phase 1: conv1 ===================
    {
        bf16x8 a1[2][3];
        const bf16x8* w1p = (const bf16x8*)w1f;
#pragma unroll
        for (int m = 0; m < 2; ++m)
#pragma unroll
            for (int k3 = 0; k3 < 3; ++k3)
                a1[m][k3] = w1p[((d * 2 + m) * 3 + k3) * 64 + lane];

        float bias[2][4];
#pragma unroll
        for (int m = 0; m < 2; ++m)
#pragma unroll
            for (int r = 0; r < 4; ++r)
                bias[m][r] = c1b[(m * 16 + g * 4 + r) * 8 + d];

        for (int q = w; q < 25; q += 4) {
            int p = q * 16 + col;
            int py = p / 20, px = p - py * 20;
            int base = py * 28 + px;
            const unsigned short* rbase = (base & 1) ? &imgs[base - 1] : &img[base];

            bf16x8 bfrag[3];
#pragma unroll
            for (int k3 = 0; k3 < 2; ++k3) {
                int grp = k3 * 4 + g;
                U8 u8;
#pragma unroll
                for (int qq = 0; qq < 4; ++qq)
                    u8.i4[qq] = *(const int*)(rbase + grp * 28 + 2 * qq);
                bfrag[k3] = u8.v;
            }
            {
                U8 u8;
                if (g == 0) {
#pragma unroll
                    for (int qq = 0; qq < 4; ++qq)
                        u8.i4[qq] = *(const int*)(rbase + 8 * 28 + 2 * qq);
                } else if (g == 1) {
#pragma unroll
                    for (int e = 0; e < 8; ++e)
                        u8.v[e] = (short)img[base + e * 28 + 8];
                } else if (g == 2) {
                    u8.i4[0] = u8.i4[1] = u8.i4[2] = u8.i4[3] = 0;
                    u8.v[0] = (short)img[base + 8 * 28 + 8];
                } else {
                    u8.i4[0] = u8.i4[1] = u8.i4[2] = u8.i4[3] = 0;
                }
                bfrag[2] = u8.v;
            }

            f32x4 acc0 = {0.f, 0.f, 0.f, 0.f};
            f32x4 acc1 = {0.f, 0.f, 0.f, 0.f};
#pragma unroll
            for (int k3 = 0; k3 < 3; ++k3) {
                acc0 = MFMA16(a1[0][k3], bfrag[k3], acc0);
                acc1 = MFMA16(a1[1][k3], bfrag[k3], acc1);
            }
            float r0[4], r1[4];
#pragma unroll
            for (int r = 0; r < 4; ++r) {
                r0[r] = fmaxf(acc0[r] + bias[0][r], 0.f);
                r1[r] = fmaxf(acc1[r] + bias[1][r], 0.f);
            }
            *(uint2*)(&interm[p * 40 + g * 4])      = make_uint2(cvtpk(r0[0], r0[1]), cvtpk(r0[2], r0[3]));
            *(uint2*)(&interm[p * 40 + 16 + g * 4]) = make_uint2(cvtpk(r1[0], r1[1]), cvtpk(r1[2], r1[3]));
        }
    }
    __syncthreads();

    // =================== phase 2: prim conv, row-split by wave ===================
    f32x4 acc[2][3];
#pragma unroll
    for (int m = 0; m < 2; ++m)
#pragma unroll
        for (int nt = 0; nt < 3; ++nt)
            acc[m][nt] = (f32x4){0.f, 0.f, 0.f, 0.f};
    {
        int abase[3];   // byte base per nt: pos0*80 + g*16
#pragma unroll
        for (int nt = 0; nt < 3; ++nt) {
            int p2 = nt * 16 + col;
            int xw = p2 / 6, yh = p2 - xw * 6;
            int pos0 = (p2 < 36) ? (yh * 40 + xw * 2) : 0;
            abase[nt] = pos0 * 80 + g * 16;
        }
        const bf16x8* w3p = (const bf16x8*)w3f;
        const char* ib = (const char*)interm;

        for (int rr = 0; rr < 2; ++rr) {
            const int ky = 2 * w + rr;
            const bf16x8* wrow = w3p + (ky * 9) * 128;
            const char* B0 = ib + abase[0] + ky * 1600;
            const char* B1 = ib + abase[1] + ky * 1600;
            const char* B2 = ib + abase[2] + ky * 1600;
#pragma unroll
            for (int kx = 0; kx < 9; ++kx) {
                bf16x8 a0  = wrow[kx * 128 + lane];
                bf16x8 a1v = wrow[kx * 128 + 64 + lane];
                bf16x8 b0 = *(const bf16x8*)(B0 + kx * 80);
                bf16x8 b1 = *(const bf16x8*)(B1 + kx * 80);
                bf16x8 b2 = *(const bf16x8*)(B2 + kx * 80);
                acc[0][0] = MFMA16(a0, b0, acc[0][0]);
                acc[1][0] = MFMA16(a1v, b0, acc[1][0]);
                acc[0][1] = MFMA16(a0, b1, acc[0][1]);
                acc[1][1] = MFMA16(a1v, b1, acc[1][1]);
                acc[0][2] = MFMA16(a0, b2, acc[0][2]);
                acc[1][2] = MFMA16(a1v, b2, acc[1][2]);
            }
        }
        // row 8 leftovers: w0:{0,1} w1:{2,3} w2:{4,5} w3:{6,7,8}
        {
            const bf16x8* wrow = w3p + 72 * 128;
            const char* B0 = ib + abase[0] + 12800;
            const char* B1 = ib + abase[1] + 12800;
            const char* B2 = ib + abase[2] + 12800;
            int kx0 = 2 * w;
            int nkx = (w == 3) ? 3 : 2;
#pragma unroll 3
            for (int q = 0; q < nkx; ++q) {
                int kx = kx0 + q;
                bf16x8 a0  = wrow[kx * 128 + lane];
                bf16x8 a1v = wrow[kx * 128 + 64 + lane];
                bf16x8 b0 = *(const bf16x8*)(B0 + kx * 80);
                bf16x8 b1 = *(const bf16x8*)(B1 + kx * 80);
                bf16x8 b2 = *(const bf16x8*)(B2 + kx * 80);
                acc[0][0] = MFMA16(a0, b0, acc[0][0]);
                acc[1][0] = MFMA16(a1v, b0, acc[1][0]);
                acc[0][1] = MFMA16(a0, b1, acc[0][1]);
                acc[1][1] = MFMA16(a1v, b1, acc[1][1]);
                acc[0][2] = MFMA16(a0, b2, acc[0][2]);
                acc[1][2] = MFMA16(a1v, b2, acc[1][2]);
            }
        }
    }
    __syncthreads();
    // ---- cross-wave reduction (f32x4 overlay on interm) ----
    f32x4* rp = (f32x4*)&interm[0];
    {
#pragma unroll
        for (int m = 0; m < 2; ++m)
#pragma unroll
            for (int nt = 0; nt < 3; ++nt)
                rp[(w * 6 + m * 3 + nt) * 64 + lane] = acc[m][nt];
    }
    __syncthreads();
    for (int idx = t; idx < 384; idx += 256) {
        int tile = idx >> 6, ls = idx & 63;
        f32x4 s = rp[tile * 64 + ls];
#pragma unroll
        for (int ww = 1; ww < 4; ++ww)
            s += rp[(ww * 6 + tile) * 64 + ls];
        int m = tile / 3, nt = tile - m * 3;
        int p2 = nt * 16 + (ls & 15);
        if (p2 < 36) {
            int gr = ls >> 4;
#pragma unroll
            for (int r = 0; r < 4; ++r) {
                int oc = m * 16 + gr * 4 + r;
                caps[(b * 8 + d) * 1152 + oc * 36 + p2] = fmaxf(s[r] + pb[oc], 0.f);
            }
        }
    }
}

// ---------------------------------------------------------------------------
// K2: routing. 576 threads (9 waves), ONE batch element per block (the R5
// structure — no spill). u,c bf16 in LDS; stage C via MFMA; logits in regs.
// ---------------------------------------------------------------------------
#define USB 1160   // u_bf row stride (bf16)
#define CSB 1160   // c_bf row stride

__global__ __launch_bounds__(576, 5) void k_route(
    const float* __restrict__ caps,  // [1024,8,1152]
    const float* __restrict__ W,     // [1152,8,16]
    const float* __restrict__ Wb,    // [1152,16]
    const float* __restrict__ ow,    // [10,10,16,1]
    const float* __restrict__ ob,    // [10]
    float* __restrict__ out)         // [1024,10]
{
    __shared__ __align__(16) unsigned short u_bf[16 * USB];  // 37,120 B
    __shared__ __align__(16) unsigned short c_bf[10 * CSB];  // 23,200 B
    __shared__ __align__(16) float sred[9 * 256];            //  9,216 B
    __shared__ __align__(16) float vv[16 * 12];
    __shared__ float ss[160];
    __shared__ float red2[16];

    const int t = threadIdx.x;
    const int lane = t & 63, wv = t >> 6;
    const int g = lane >> 4, col = lane & 15;
    const int b = blockIdx.x;
    const int n0 = 2 * t;

    // ---- stage A: u[f][n] -> bf16 ----
    {
        const int nl = t >> 2, fq = t & 3;
        for (int base = 0; base < 1152; base += 144) {
            int n = base + nl;
            float cv[8];
#pragma unroll
            for (int e = 0; e < 8; ++e) cv[e] = caps[(b * 8 + e) * 1152 + n];
            float4 a4 = ((const float4*)(Wb + n * 16))[fq];
#pragma unroll
            for (int e = 0; e < 8; ++e) {
                float4 w4 = ((const float4*)(W + n * 128 + e * 16))[fq];
                a4.x += cv[e] * w4.x; a4.y += cv[e] * w4.y;
                a4.z += cv[e] * w4.z; a4.w += cv[e] * w4.w;
            }
            u_bf[(fq * 4 + 0) * USB + n] = f2bf(a4.x);
            u_bf[(fq * 4 + 1) * USB + n] = f2bf(a4.y);
            u_bf[(fq * 4 + 2) * USB + n] = f2bf(a4.z);
            u_bf[(fq * 4 + 3) * USB + n] = f2bf(a4.w);
        }
    }
    float breg[2][10];
#pragma unroll
    for (int s = 0; s < 2; ++s)
#pragma unroll
        for (int jj = 0; jj < 10; ++jj) breg[s][jj] = 0.f;
    __syncthreads();

    const int jrow = (col < 10) ? col : 9;   // A-frag row clamp (rows 10-15 unused)

    for (int iter = 0; iter < 3; ++iter) {
        // ---- stage B: thread-local softmax -> c_bf (2 n's packed per b32) ----
        {
            float cv2[2][10];
#pragma unroll
            for (int s = 0; s < 2; ++s) {
                float m = breg[s][0];
#pragma unroll
                for (int jj = 1; jj < 10; ++jj) m = fmaxf(m, breg[s][jj]);
                float sum = 0.f;
#pragma unroll
                for (int jj = 0; jj < 10; ++jj) { cv2[s][jj] = __expf(breg[s][jj] - m); sum += cv2[s][jj]; }
                float inv = 1.f / sum;
#pragma unroll
                for (int jj = 0; jj < 10; ++jj) cv2[s][jj] *= inv;
            }
#pragma unroll
            for (int jj = 0; jj < 10; ++jj)
                *(unsigned*)(&c_bf[jj * CSB + n0]) = cvtpk(cv2[0][jj], cv2[1][jj]);
        }
        __syncthreads();
        // ---- stage C: s[j][f] via MFMA, wave wv owns n-chunk [wv*128, +128) ----
        {
            f32x4 sp = {0.f, 0.f, 0.f, 0.f};
#pragma unroll
            for (int mf = 0; mf < 4; ++mf) {
                int nk = wv * 128 + mf * 32 + g * 8;
                bf16x8 af = *(const bf16x8*)(&c_bf[jrow * CSB + nk]);
                bf16x8 bf = *(const bf16x8*)(&u_bf[col * USB + nk]);
                sp = MFMA16(af, bf, sp);
            }
            *(f32x4*)(&sred[wv * 256 + lane * 4]) = sp;
        }
        __syncthreads();
        // ---- reduce 9 wave-partials -> ss[j][f] ----
        if (t < 160) {
            int j = t >> 4, f = t & 15;
            int li = ((j >> 2) * 16 + f) * 4 + (j & 3);
            float s = 0.f;
#pragma unroll
            for (int ww = 0; ww < 9; ++ww) s += sred[ww * 256 + li];
            ss[j * 16 + f] = s;
        }
        __syncthreads();
        // ---- squash -> vv[f][j] ----
        if (t < 16) {
            float sv[10], l2 = 0.f, l1 = 0.f;
#pragma unroll
            for (int jj = 0; jj < 10; ++jj) {
                sv[jj] = ss[jj * 16 + t];
                l2 += sv[jj] * sv[jj]; l1 += fabsf(sv[jj]);
            }
            l2 = sqrtf(l2);
            float scale = l2 / (1.f + l2) / l1;
#pragma unroll
            for (int jj = 0; jj < 10; ++jj) vv[t * 12 + jj] = sv[jj] * scale;
        }
        __syncthreads();
        // ---- stage E: breg[s][j] += sum_f u_bf[f][n0+s] * vv[f][j] ----
        if (iter < 2) {
#pragma unroll
            for (int f = 0; f < 16; ++f) {
                unsigned pair = *(const unsigned*)(&u_bf[f * USB + n0]);
                float ux = __builtin_bit_cast(float, pair << 16);
                float uy = __builtin_bit_cast(float, pair & 0xffff0000u);
                f32x4 v0 = *(const f32x4*)(&vv[f * 12]);
                f32x4 v1 = *(const f32x4*)(&vv[f * 12 + 4]);
                float2 v2 = *(const float2*)(&vv[f * 12 + 8]);
                breg[0][0] += ux * v0.x; breg[1][0] += uy * v0.x;
                breg[0][1] += ux * v0.y; breg[1][1] += uy * v0.y;
                breg[0][2] += ux * v0.z; breg[1][2] += uy * v0.z;
                breg[0][3] += ux * v0.w; breg[1][3] += uy * v0.w;
                breg[0][4] += ux * v1.x; breg[1][4] += uy * v1.x;
                breg[0][5] += ux * v1.y; breg[1][5] += uy * v1.y;
                breg[0][6] += ux * v1.z; breg[1][6] += uy * v1.z;
                breg[0][7] += ux * v1.w; breg[1][7] += uy * v1.w;
                breg[0][8] += ux * v2.x; breg[1][8] += uy * v2.x;
                breg[0][9] += ux * v2.y; breg[1][9] += uy * v2.y;
            }
        }
        __syncthreads();
    }

    // ---- output head + softmax ----
    if (t < 10) {
        float l = ob[t];
#pragma unroll
        for (int i2 = 0; i2 < 10; ++i2)
#pragma unroll
            for (int ff = 0; ff < 16; ++ff)
                l += vv[ff * 12 + i2] * ow[t * 160 + i2 * 16 + ff];
        red2[t] = l;
    }
    __syncthreads();
    if (t == 0) {
        float m = -1e30f;
        for (int o = 0; o < 10; ++o) m = fmaxf(m, red2[o]);
        float sum = 0.f; float e[10];
        for (int o = 0; o < 10; ++o) { e[o] = __expf(red2[o] - m); sum += e[o]; }
        float inv = 1.f / sum;
        for (int o = 0; o < 10; ++o) out[b * 10 + o] = e[o] * inv;
    }
}

extern "C" void kernel_launch(void* const* d_in, const int* in_sizes, int n_in,
                              void* d_out, int out_size, void* d_ws, size_t ws_size,
                              hipStream_t stream) {
    const float* x     = (const float*)d_in[0];
    const float* c1w   = (const float*)d_in[1];
    const float* c1b   = (const float*)d_in[2];
    const float* pw    = (const float*)d_in[3];
    const float* pb    = (const float*)d_in[4];
    const float* digW  = (const float*)d_in[5];
    const float* digWb = (const float*)d_in[6];
    const float* outw  = (const float*)d_in[7];
    const float* outb  = (const float*)d_in[8];
    float* out = (float*)d_out;

    float* caps = (float*)d_ws;
    unsigned short* w1f = (unsigned short*)((char*)d_ws + CAPS_BYTES);
    unsigned short* w3f = w1f + A1F_ELEMS;

    k_prep<<<dim3(420), dim3(256), 0, stream>>>(c1w, pw, w1f, w3f);
    k_conv<<<dim3(8192), dim3(256), 0, stream>>>(x, c1b, pb, w1f, w3f, caps);
    k_route<<<dim3(1024), dim3(576), 0, stream>>>(caps, digW, digWb, outw, outb, out);
}

// Round 8
// 178.315 us; speedup vs baseline: 1.5887x; 1.0178x over previous
//
#include <hip/hip_runtime.h>
#include <math.h>

typedef __attribute__((ext_vector_type(8))) short bf16x8;
typedef __attribute__((ext_vector_type(4))) float f32x4;
#define MFMA16(a, b, c) __builtin_amdgcn_mfma_f32_16x16x32_bf16(a, b, c, 0, 0, 0)

union U8 { bf16x8 v; int i4[4]; };

__device__ __forceinline__ unsigned short f2bf(float x) {
    unsigned u = __builtin_bit_cast(unsigned, x);
    unsigned r = (u + 0x7fffu + ((u >> 16) & 1u)) >> 16;   // RNE
    return (unsigned short)r;
}
// packed RNE f32x2 -> bf16x2
__device__ __forceinline__ unsigned cvtpk(float lo, float hi) {
    unsigned r;
    asm("v_cvt_pk_bf16_f32 %0, %1, %2" : "=v"(r) : "v"(lo), "v"(hi));
    return r;
}

// conv1 K-permutation sigma (same on A and B, cancels):
__device__ __forceinline__ int koff_of(int kidx) {
    int grp = kidx >> 3, e = kidx & 7;
    if (grp < 9)  return grp * 9 + e;
    if (grp == 9) return e * 9 + 8;
    if (grp == 10) return (e == 0) ? 80 : -1;
    return -1;
}

#define CAPS_BYTES 37748736
#define A1F_ELEMS  24576
#define W3F_ELEMS  82944    // 81 taps * 2 m * 64 lanes * 8 e
#define WBF_ELEMS  147456   // 1152 * 8 * 16 bf16 copy of dig_W

// ---------------------------------------------------------------------------
// K0: pack conv weights into MFMA fragment layout + dig_W -> bf16
// ---------------------------------------------------------------------------
__global__ void k_prep(const float* __restrict__ c1w,  // [256,1,9,9]
                       const float* __restrict__ pw,   // [32,32,1,9,9]
                       const float* __restrict__ digW, // [1152,8,16]
                       unsigned short* __restrict__ w1f,
                       unsigned short* __restrict__ w3f,
                       unsigned short* __restrict__ wbf)
{
    int idx = blockIdx.x * 256 + threadIdx.x;
    if (idx < A1F_ELEMS) {
        int e = idx & 7, lane = (idx >> 3) & 63, f = idx >> 9;
        int k3 = f % 3, m = (f / 3) & 1, d = f / 6;
        int ch = (lane & 15) + m * 16;
        int kidx = k3 * 32 + ((lane >> 4) << 3) + e;
        int ko = koff_of(kidx);
        w1f[idx] = f2bf(ko >= 0 ? c1w[(ch * 8 + d) * 81 + ko] : 0.f);
    } else if (idx < A1F_ELEMS + W3F_ELEMS) {
        int j = idx - A1F_ELEMS;
        int e = j & 7, lane = (j >> 3) & 63, f = j >> 9;
        int m = f & 1, tap = f >> 1;
        int oc = (lane & 15) + m * 16;
        int i = ((lane >> 4) << 3) + e;
        w3f[j] = f2bf(pw[oc * 2592 + i * 81 + tap]);
    } else if (idx < A1F_ELEMS + W3F_ELEMS + WBF_ELEMS) {
        int j = idx - A1F_ELEMS - W3F_ELEMS;
        wbf[j] = f2bf(digW[j]);
    }
}

// ---------------------------------------------------------------------------
// K1: fused conv1 + prim conv. One block = one (b,d) slice. 4 blocks/CU.
// interm: parity-quadrant layout: position (py,px) stored at
//   idx = ((py&1)*10 + (py>>1))*20 + (px&1)*10 + (px>>1), [idx][ch40] u16.
// -> phase-2 lane deltas have odd bank strides; reads <=3-way, writes 2-way.
// All phase-2 read offsets remain compile-time immediates.
// ---------------------------------------------------------------------------
__global__ __launch_bounds__(256, 4) void k_conv(
    const float* __restrict__ x,    // [1024,1,28,28]
    const float* __restrict__ c1b,  // [256]
    const float* __restrict__ pb,   // [32]
    const unsigned short* __restrict__ w1f,
    const unsigned short* __restrict__ w3f,
    float* __restrict__ caps)       // [1024,8,1152]
{
    __shared__ __align__(16) unsigned short img[800];
    __shared__ __align__(16) unsigned short imgs[800];          // shifted by 1
    __shared__ __align__(128) unsigned short interm[400 * 40];  // 32000 B

    const int t = threadIdx.x;
    const int lane = t & 63, w = t >> 6;
    const int g = lane >> 4, col = lane & 15;
    const int b = blockIdx.x >> 3, d = blockIdx.x & 7;

    for (int idx = t; idx < 784; idx += 256) {
        unsigned short v = f2bf(x[b * 784 + idx]);
        img[idx] = v;
        if (idx > 0) imgs[idx - 1] = v;
    }
    __syncthreads();

    // =================== phase 1: conv1 ===================
    {
        bf16x8 a1[2][3];
        const bf16x8* w1p = (const bf16x8*)w1f;
#pragma unroll
        for (int m = 0; m < 2; ++m)
#pragma unroll
            for (int k3 = 0; k3 < 3; ++k3)
                a1[m][k3] = w1p[((d * 2 + m) * 3 + k3) * 64 + lane];

        float bias[2][4];
#pragma unroll
        for (int m = 0; m < 2; ++m)
#pragma unroll
            for (int r = 0; r < 4; ++r)
                bias[m][r] = c1b[(m * 16 + g * 4 + r) * 8 + d];

        for (int q = w; q < 25; q += 4) {
            int p = q * 16 + col;
            int py = p / 20, px = p - py * 20;
            int base = py * 28 + px;
            const unsigned short* rbase = (base & 1) ? &imgs[base - 1] : &img[base];

            bf16x8 bfrag[3];
#pragma unroll
            for (int k3 = 0; k3 < 2; ++k3) {
                int grp = k3 * 4 + g;
                U8 u8;
#pragma unroll
                for (int qq = 0; qq < 4; ++qq)
                    u8.i4[qq] = *(const int*)(rbase + grp * 28 + 2 * qq);
                bfrag[k3] = u8.v;
            }
            {
                U8 u8;
                if (g == 0) {
#pragma unroll
                    for (int qq = 0; qq < 4; ++qq)
                        u8.i4[qq] = *(const int*)(rbase + 8 * 28 + 2 * qq);
                } else if (g == 1) {
#pragma unroll
                    for (int e = 0; e < 8; ++e)
                        u8.v[e] = (short)img[base + e * 28 + 8];
                } else if (g == 2) {
                    u8.i4[0] = u8.i4[1] = u8.i4[2] = u8.i4[3] = 0;
                    u8.v[0] = (short)img[base + 8 * 28 + 8];
                } else {
                    u8.i4[0] = u8.i4[1] = u8.i4[2] = u8.i4[3] = 0;
                }
                bfrag[2] = u8.v;
            }

            f32x4 acc0 = {0.f, 0.f, 0.f, 0.f};
            f32x4 acc1 = {0.f, 0.f, 0.f, 0.f};
#pragma unroll
            for (int k3 = 0; k3 < 3; ++k3) {
                acc0 = MFMA16(a1[0][k3], bfrag[k3], acc0);
                acc1 = MFMA16(a1[1][k3], bfrag[k3], acc1);
            }
            float r0[4], r1[4];
#pragma unroll
            for (int r = 0; r < 4; ++r) {
                r0[r] = fmaxf(acc0[r] + bias[0][r], 0.f);
                r1[r] = fmaxf(acc1[r] + bias[1][r], 0.f);
            }
            // parity-quadrant store index
            int rr2 = (py & 1) * 10 + (py >> 1);
            int cc2 = (px & 1) * 10 + (px >> 1);
            int sidx = rr2 * 20 + cc2;
            *(uint2*)(&interm[sidx * 40 + g * 4])      = make_uint2(cvtpk(r0[0], r0[1]), cvtpk(r0[2], r0[3]));
            *(uint2*)(&interm[sidx * 40 + 16 + g * 4]) = make_uint2(cvtpk(r1[0], r1[1]), cvtpk(r1[2], r1[3]));
        }
    }
    __syncthreads();

    // =================== phase 2: prim conv, row-split by wave ===================
    // read pos (2yh+ky, 2xw+kx) lives at r=(ky&1)*10+yh+(ky>>1), c=(kx&1)*10+xw+(kx>>1)
    f32x4 acc[2][3];
#pragma unroll
    for (int m = 0; m < 2; ++m)
#pragma unroll
        for (int nt = 0; nt < 3; ++nt)
            acc[m][nt] = (f32x4){0.f, 0.f, 0.f, 0.f};
    {
        // byte offset of kx within a row: ((kx&1)*10 + (kx>>1)) * 80
        const int KOFF[9] = {0, 800, 80, 880, 160, 960, 240, 1040, 320};
        int abase[3];   // byte base per nt: (yh*20 + xw)*80 + g*16  (transposed col map)
#pragma unroll
        for (int nt = 0; nt < 3; ++nt) {
            int p2 = nt * 16 + col;
            int xw, yh;
            if (p2 < 36) { yh = p2 / 6; xw = p2 - yh * 6; } else { yh = 0; xw = 0; }
            abase[nt] = (yh * 20 + xw) * 80 + g * 16;
        }
        const bf16x8* w3p = (const bf16x8*)w3f;
        const char* ib = (const char*)interm;

        for (int rr = 0; rr < 2; ++rr) {
            const int ky = 2 * w + rr;
            const int roff = (rr == 0) ? (w * 1600) : ((10 + w) * 1600);
            const bf16x8* wrow = w3p + (ky * 9) * 128;
            const char* B0 = ib + abase[0] + roff;
            const char* B1 = ib + abase[1] + roff;
            const char* B2 = ib + abase[2] + roff;
#pragma unroll
            for (int kx = 0; kx < 9; ++kx) {
                bf16x8 a0  = wrow[kx * 128 + lane];
                bf16x8 a1v = wrow[kx * 128 + 64 + lane];
                bf16x8 b0 = *(const bf16x8*)(B0 + KOFF[kx]);
                bf16x8 b1 = *(const bf16x8*)(B1 + KOFF[kx]);
                bf16x8 b2 = *(const bf16x8*)(B2 + KOFF[kx]);
                acc[0][0] = MFMA16(a0, b0, acc[0][0]);
                acc[1][0] = MFMA16(a1v, b0, acc[1][0]);
                acc[0][1] = MFMA16(a0, b1, acc[0][1]);
                acc[1][1] = MFMA16(a1v, b1, acc[1][1]);
                acc[0][2] = MFMA16(a0, b2, acc[0][2]);
                acc[1][2] = MFMA16(a1v, b2, acc[1][2]);
            }
        }
        // row 8 leftovers: ky=8 -> roff = 4*1600. w0:{0,1} w1:{2,3} w2:{4,5} w3:{6,7,8}
        {
            const bf16x8* wrow = w3p + 72 * 128;
            const char* B0 = ib + abase[0] + 6400;
            const char* B1 = ib + abase[1] + 6400;
            const char* B2 = ib + abase[2] + 6400;
            int kx0 = 2 * w;
            int nkx = (w == 3) ? 3 : 2;
#pragma unroll 3
            for (int q = 0; q < nkx; ++q) {
                int kx = kx0 + q;
                bf16x8 a0  = wrow[kx * 128 + lane];
                bf16x8 a1v = wrow[kx * 128 + 64 + lane];
                bf16x8 b0 = *(const bf16x8*)(B0 + KOFF[kx]);
                bf16x8 b1 = *(const bf16x8*)(B1 + KOFF[kx]);
                bf16x8 b2 = *(const bf16x8*)(B2 + KOFF[kx]);
                acc[0][0] = MFMA16(a0, b0, acc[0][0]);
                acc[1][0] = MFMA16(a1v, b0, acc[1][0]);
                acc[0][1] = MFMA16(a0, b1, acc[0][1]);
                acc[1][1] = MFMA16(a1v, b1, acc[1][1]);
                acc[0][2] = MFMA16(a0, b2, acc[0][2]);
                acc[1][2] = MFMA16(a1v, b2, acc[1][2]);
            }
        }
    }
    __syncthreads();
    // ---- cross-wave reduction (f32x4 overlay on interm) ----
    f32x4* rp = (f32x4*)&interm[0];
    {
#pragma unroll
        for (int m = 0; m < 2; ++m)
#pragma unroll
            for (int nt = 0; nt < 3; ++nt)
                rp[(w * 6 + m * 3 + nt) * 64 + lane] = acc[m][nt];
    }
    __syncthreads();
    for (int idx = t; idx < 384; idx += 256) {
        int tile = idx >> 6, ls = idx & 63;
        f32x4 s = rp[tile * 64 + ls];
#pragma unroll
        for (int ww = 1; ww < 4; ++ww)
            s += rp[(ww * 6 + tile) * 64 + ls];
        int m = tile / 3, nt = tile - m * 3;
        int p2 = nt * 16 + (ls & 15);
        if (p2 < 36) {
            int yh = p2 / 6, xw = p2 - yh * 6;   // transposed col map
            int gr = ls >> 4;
#pragma unroll
            for (int r = 0; r < 4; ++r) {
                int oc = m * 16 + gr * 4 + r;
                caps[(b * 8 + d) * 1152 + oc * 36 + xw * 6 + yh] = fmaxf(s[r] + pb[oc], 0.f);
            }
        }
    }
}

// ---------------------------------------------------------------------------
// K2: routing. 576 threads (9 waves), one b per block. W in bf16 (halved L2).
// ---------------------------------------------------------------------------
#define USB 1160
#define CSB 1160

__global__ __launch_bounds__(576, 5) void k_route(
    const float* __restrict__ caps,  // [1024,8,1152]
    const unsigned short* __restrict__ Wbf,  // [1152,8,16] bf16
    const float* __restrict__ Wb,    // [1152,16]
    const float* __restrict__ ow,    // [10,10,16,1]
    const float* __restrict__ ob,    // [10]
    float* __restrict__ out)         // [1024,10]
{
    __shared__ __align__(16) unsigned short u_bf[16 * USB];  // 37,120 B
    __shared__ __align__(16) unsigned short c_bf[10 * CSB];  // 23,200 B
    __shared__ __align__(16) float sred[9 * 256];            //  9,216 B
    __shared__ __align__(16) float vv[16 * 12];
    __shared__ float ss[160];
    __shared__ float red2[16];

    const int t = threadIdx.x;
    const int lane = t & 63, wv = t >> 6;
    const int g = lane >> 4, col = lane & 15;
    const int b = blockIdx.x;
    const int n0 = 2 * t;

    // ---- stage A: u[f][n] -> bf16 (W streamed as bf16) ----
    {
        const int nl = t >> 2, fq = t & 3;
        for (int base = 0; base < 1152; base += 144) {
            int n = base + nl;
            float cv[8];
#pragma unroll
            for (int e = 0; e < 8; ++e) cv[e] = caps[(b * 8 + e) * 1152 + n];
            float4 a4 = ((const float4*)(Wb + n * 16))[fq];
#pragma unroll
            for (int e = 0; e < 8; ++e) {
                uint2 wp = *(const uint2*)(&Wbf[n * 128 + e * 16 + fq * 4]);
                float w0 = __builtin_bit_cast(float, wp.x << 16);
                float w1 = __builtin_bit_cast(float, wp.x & 0xffff0000u);
                float w2 = __builtin_bit_cast(float, wp.y << 16);
                float w3 = __builtin_bit_cast(float, wp.y & 0xffff0000u);
                a4.x += cv[e] * w0; a4.y += cv[e] * w1;
                a4.z += cv[e] * w2; a4.w += cv[e] * w3;
            }
            *(unsigned*)(&u_bf[(fq * 4 + 0) * USB + n]) ; // no-op guard (kept for clarity)
            u_bf[(fq * 4 + 0) * USB + n] = f2bf(a4.x);
            u_bf[(fq * 4 + 1) * USB + n] = f2bf(a4.y);
            u_bf[(fq * 4 + 2) * USB + n] = f2bf(a4.z);
            u_bf[(fq * 4 + 3) * USB + n] = f2bf(a4.w);
        }
    }
    float breg[2][10];
#pragma unroll
    for (int s = 0; s < 2; ++s)
#pragma unroll
        for (int jj = 0; jj < 10; ++jj) breg[s][jj] = 0.f;
    __syncthreads();

    const int jrow = (col < 10) ? col : 9;

    for (int iter = 0; iter < 3; ++iter) {
        // ---- stage B: thread-local softmax -> c_bf ----
        {
            float cv2[2][10];
#pragma unroll
            for (int s = 0; s < 2; ++s) {
                float m = breg[s][0];
#pragma unroll
                for (int jj = 1; jj < 10; ++jj) m = fmaxf(m, breg[s][jj]);
                float sum = 0.f;
#pragma unroll
                for (int jj = 0; jj < 10; ++jj) { cv2[s][jj] = __expf(breg[s][jj] - m); sum += cv2[s][jj]; }
                float inv = 1.f / sum;
#pragma unroll
                for (int jj = 0; jj < 10; ++jj) cv2[s][jj] *= inv;
            }
#pragma unroll
            for (int jj = 0; jj < 10; ++jj)
                *(unsigned*)(&c_bf[jj * CSB + n0]) = cvtpk(cv2[0][jj], cv2[1][jj]);
        }
        __syncthreads();
        // ---- stage C: s[j][f] via MFMA ----
        {
            f32x4 sp = {0.f, 0.f, 0.f, 0.f};
#pragma unroll
            for (int mf = 0; mf < 4; ++mf) {
                int nk = wv * 128 + mf * 32 + g * 8;
                bf16x8 af = *(const bf16x8*)(&c_bf[jrow * CSB + nk]);
                bf16x8 bf = *(const bf16x8*)(&u_bf[col * USB + nk]);
                sp = MFMA16(af, bf, sp);
            }
            *(f32x4*)(&sred[wv * 256 + lane * 4]) = sp;
        }
        __syncthreads();
        // ---- reduce 9 wave-partials -> ss[j][f] ----
        if (t < 160) {
            int j = t >> 4, f = t & 15;
            int li = ((j >> 2) * 16 + f) * 4 + (j & 3);
            float s = 0.f;
#pragma unroll
            for (int ww = 0; ww < 9; ++ww) s += sred[ww * 256 + li];
            ss[j * 16 + f] = s;
        }
        __syncthreads();
        // ---- squash -> vv[f][j] ----
        if (t < 16) {
            float sv[10], l2 = 0.f, l1 = 0.f;
#pragma unroll
            for (int jj = 0; jj < 10; ++jj) {
                sv[jj] = ss[jj * 16 + t];
                l2 += sv[jj] * sv[jj]; l1 += fabsf(sv[jj]);
            }
            l2 = sqrtf(l2);
            float scale = l2 / (1.f + l2) / l1;
#pragma unroll
            for (int jj = 0; jj < 10; ++jj) vv[t * 12 + jj] = sv[jj] * scale;
        }
        __syncthreads();
        // ---- stage E: breg += u^T v ----
        if (iter < 2) {
#pragma unroll
            for (int f = 0; f < 16; ++f) {
                unsigned pair = *(const unsigned*)(&u_bf[f * USB + n0]);
                float ux = __builtin_bit_cast(float, pair << 16);
                float uy = __builtin_bit_cast(float, pair & 0xffff0000u);
                f32x4 v0 = *(const f32x4*)(&vv[f * 12]);
                f32x4 v1 = *(const f32x4*)(&vv[f * 12 + 4]);
                float2 v2 = *(const float2*)(&vv[f * 12 + 8]);
                breg[0][0] += ux * v0.x; breg[1][0] += uy * v0.x;
                breg[0][1] += ux * v0.y; breg[1][1] += uy * v0.y;
                breg[0][2] += ux * v0.z; breg[1][2] += uy * v0.z;
                breg[0][3] += ux * v0.w; breg[1][3] += uy * v0.w;
                breg[0][4] += ux * v1.x; breg[1][4] += uy * v1.x;
                breg[0][5] += ux * v1.y; breg[1][5] += uy * v1.y;
                breg[0][6] += ux * v1.z; breg[1][6] += uy * v1.z;
                breg[0][7] += ux * v1.w; breg[1][7] += uy * v1.w;
                breg[0][8] += ux * v2.x; breg[1][8] += uy * v2.x;
                breg[0][9] += ux * v2.y; breg[1][9] += uy * v2.y;
            }
        }
        __syncthreads();
    }

    // ---- output head + softmax ----
    if (t < 10) {
        float l = ob[t];
#pragma unroll
        for (int i2 = 0; i2 < 10; ++i2)
#pragma unroll
            for (int ff = 0; ff < 16; ++ff)
                l += vv[ff * 12 + i2] * ow[t * 160 + i2 * 16 + ff];
        red2[t] = l;
    }
    __syncthreads();
    if (t == 0) {
        float m = -1e30f;
        for (int o = 0; o < 10; ++o) m = fmaxf(m, red2[o]);
        float sum = 0.f; float e[10];
        for (int o = 0; o < 10; ++o) { e[o] = __expf(red2[o] - m); sum += e[o]; }
        float inv = 1.f / sum;
        for (int o = 0; o < 10; ++o) out[b * 10 + o] = e[o] * inv;
    }
}

extern "C" void kernel_launch(void* const* d_in, const int* in_sizes, int n_in,
                              void* d_out, int out_size, void* d_ws, size_t ws_size,
                              hipStream_t stream) {
    const float* x     = (const float*)d_in[0];
    const float* c1w   = (const float*)d_in[1];
    const float* c1b   = (const float*)d_in[2];
    const float* pw    = (const float*)d_in[3];
    const float* pb    = (const float*)d_in[4];
    const float* digW  = (const float*)d_in[5];
    const float* digWb = (const float*)d_in[6];
    const float* outw  = (const float*)d_in[7];
    const float* outb  = (const float*)d_in[8];
    float* out = (float*)d_out;

    float* caps = (float*)d_ws;
    unsigned short* w1f = (unsigned short*)((char*)d_ws + CAPS_BYTES);
    unsigned short* w3f = w1f + A1F_ELEMS;
    unsigned short* wbf = w3f + W3F_ELEMS;

    k_prep<<<dim3(996), dim3(256), 0, stream>>>(c1w, pw, digW, w1f, w3f, wbf);
    k_conv<<<dim3(8192), dim3(256), 0, stream>>>(x, c1b, pb, w1f, w3f, caps);
    k_route<<<dim3(1024), dim3(576), 0, stream>>>(caps, wbf, digWb, outw, outb, out);
}

// Round 9
// 169.235 us; speedup vs baseline: 1.6740x; 1.0537x over previous
//
#include <hip/hip_runtime.h>
#include <math.h>

typedef __attribute__((ext_vector_type(8))) short bf16x8;
typedef __attribute__((ext_vector_type(4))) float f32x4;
#define MFMA16(a, b, c) __builtin_amdgcn_mfma_f32_16x16x32_bf16(a, b, c, 0, 0, 0)

union U8 { bf16x8 v; int i4[4]; };

__device__ __forceinline__ unsigned short f2bf(float x) {
    unsigned u = __builtin_bit_cast(unsigned, x);
    unsigned r = (u + 0x7fffu + ((u >> 16) & 1u)) >> 16;   // RNE
    return (unsigned short)r;
}
// packed RNE f32x2 -> bf16x2
__device__ __forceinline__ unsigned cvtpk(float lo, float hi) {
    unsigned r;
    asm("v_cvt_pk_bf16_f32 %0, %1, %2" : "=v"(r) : "v"(lo), "v"(hi));
    return r;
}

// conv1 K-permutation sigma (same on A and B, cancels):
__device__ __forceinline__ int koff_of(int kidx) {
    int grp = kidx >> 3, e = kidx & 7;
    if (grp < 9)  return grp * 9 + e;
    if (grp == 9) return e * 9 + 8;
    if (grp == 10) return (e == 0) ? 80 : -1;
    return -1;
}

#define CAPS_BYTES 37748736
#define A1F_ELEMS  24576
#define W3F_ELEMS  82944    // 81 taps * 2 m * 64 lanes * 8 e
#define WBF_ELEMS  147456   // 1152 * 8 * 16 bf16 copy of dig_W

// ---------------------------------------------------------------------------
// K0: pack conv weights into MFMA fragment layout + dig_W -> bf16
// ---------------------------------------------------------------------------
__global__ void k_prep(const float* __restrict__ c1w,  // [256,1,9,9]
                       const float* __restrict__ pw,   // [32,32,1,9,9]
                       const float* __restrict__ digW, // [1152,8,16]
                       unsigned short* __restrict__ w1f,
                       unsigned short* __restrict__ w3f,
                       unsigned short* __restrict__ wbf)
{
    int idx = blockIdx.x * 256 + threadIdx.x;
    if (idx < A1F_ELEMS) {
        int e = idx & 7, lane = (idx >> 3) & 63, f = idx >> 9;
        int k3 = f % 3, m = (f / 3) & 1, d = f / 6;
        int ch = (lane & 15) + m * 16;
        int kidx = k3 * 32 + ((lane >> 4) << 3) + e;
        int ko = koff_of(kidx);
        w1f[idx] = f2bf(ko >= 0 ? c1w[(ch * 8 + d) * 81 + ko] : 0.f);
    } else if (idx < A1F_ELEMS + W3F_ELEMS) {
        int j = idx - A1F_ELEMS;
        int e = j & 7, lane = (j >> 3) & 63, f = j >> 9;
        int m = f & 1, tap = f >> 1;
        int oc = (lane & 15) + m * 16;
        int i = ((lane >> 4) << 3) + e;
        w3f[j] = f2bf(pw[oc * 2592 + i * 81 + tap]);
    } else if (idx < A1F_ELEMS + W3F_ELEMS + WBF_ELEMS) {
        int j = idx - A1F_ELEMS - W3F_ELEMS;
        wbf[j] = f2bf(digW[j]);
    }
}

// ---------------------------------------------------------------------------
// K1: fused conv1 + prim conv (R7 measured-best variant: linear [pos][ch40]
// layout, contiguous kx offsets, row-split phase 2). 4 blocks/CU.
// ---------------------------------------------------------------------------
__global__ __launch_bounds__(256, 4) void k_conv(
    const float* __restrict__ x,    // [1024,1,28,28]
    const float* __restrict__ c1b,  // [256]
    const float* __restrict__ pb,   // [32]
    const unsigned short* __restrict__ w1f,
    const unsigned short* __restrict__ w3f,
    float* __restrict__ caps)       // [1024,8,1152]
{
    __shared__ __align__(16) unsigned short img[800];
    __shared__ __align__(16) unsigned short imgs[800];          // shifted by 1
    __shared__ __align__(128) unsigned short interm[400 * 40];  // 32000 B

    const int t = threadIdx.x;
    const int lane = t & 63, w = t >> 6;
    const int g = lane >> 4, col = lane & 15;
    const int b = blockIdx.x >> 3, d = blockIdx.x & 7;

    for (int idx = t; idx < 784; idx += 256) {
        unsigned short v = f2bf(x[b * 784 + idx]);
        img[idx] = v;
        if (idx > 0) imgs[idx - 1] = v;
    }
    __syncthreads();

    // =================== phase 1: conv1 ===================
    {
        bf16x8 a1[2][3];
        const bf16x8* w1p = (const bf16x8*)w1f;
#pragma unroll
        for (int m = 0; m < 2; ++m)
#pragma unroll
            for (int k3 = 0; k3 < 3; ++k3)
                a1[m][k3] = w1p[((d * 2 + m) * 3 + k3) * 64 + lane];

        float bias[2][4];
#pragma unroll
        for (int m = 0; m < 2; ++m)
#pragma unroll
            for (int r = 0; r < 4; ++r)
                bias[m][r] = c1b[(m * 16 + g * 4 + r) * 8 + d];

        for (int q = w; q < 25; q += 4) {
            int p = q * 16 + col;
            int py = p / 20, px = p - py * 20;
            int base = py * 28 + px;
            const unsigned short* rbase = (base & 1) ? &imgs[base - 1] : &img[base];

            bf16x8 bfrag[3];
#pragma unroll
            for (int k3 = 0; k3 < 2; ++k3) {
                int grp = k3 * 4 + g;
                U8 u8;
#pragma unroll
                for (int qq = 0; qq < 4; ++qq)
                    u8.i4[qq] = *(const int*)(rbase + grp * 28 + 2 * qq);
                bfrag[k3] = u8.v;
            }
            {
                U8 u8;
                if (g == 0) {
#pragma unroll
                    for (int qq = 0; qq < 4; ++qq)
                        u8.i4[qq] = *(const int*)(rbase + 8 * 28 + 2 * qq);
                } else if (g == 1) {
#pragma unroll
                    for (int e = 0; e < 8; ++e)
                        u8.v[e] = (short)img[base + e * 28 + 8];
                } else if (g == 2) {
                    u8.i4[0] = u8.i4[1] = u8.i4[2] = u8.i4[3] = 0;
                    u8.v[0] = (short)img[base + 8 * 28 + 8];
                } else {
                    u8.i4[0] = u8.i4[1] = u8.i4[2] = u8.i4[3] = 0;
                }
                bfrag[2] = u8.v;
            }

            f32x4 acc0 = {0.f, 0.f, 0.f, 0.f};
            f32x4 acc1 = {0.f, 0.f, 0.f, 0.f};
#pragma unroll
            for (int k3 = 0; k3 < 3; ++k3) {
                acc0 = MFMA16(a1[0][k3], bfrag[k3], acc0);
                acc1 = MFMA16(a1[1][k3], bfrag[k3], acc1);
            }
            float r0[4], r1[4];
#pragma unroll
            for (int r = 0; r < 4; ++r) {
                r0[r] = fmaxf(acc0[r] + bias[0][r], 0.f);
                r1[r] = fmaxf(acc1[r] + bias[1][r], 0.f);
            }
            *(uint2*)(&interm[p * 40 + g * 4])      = make_uint2(cvtpk(r0[0], r0[1]), cvtpk(r0[2], r0[3]));
            *(uint2*)(&interm[p * 40 + 16 + g * 4]) = make_uint2(cvtpk(r1[0], r1[1]), cvtpk(r1[2], r1[3]));
        }
    }
    __syncthreads();

    // =================== phase 2: prim conv, row-split by wave ===================
    f32x4 acc[2][3];
#pragma unroll
    for (int m = 0; m < 2; ++m)
#pragma unroll
        for (int nt = 0; nt < 3; ++nt)
            acc[m][nt] = (f32x4){0.f, 0.f, 0.f, 0.f};
    {
        int abase[3];   // byte base per nt: pos0*80 + g*16
#pragma unroll
        for (int nt = 0; nt < 3; ++nt) {
            int p2 = nt * 16 + col;
            int xw = p2 / 6, yh = p2 - xw * 6;
            int pos0 = (p2 < 36) ? (yh * 40 + xw * 2) : 0;
            abase[nt] = pos0 * 80 + g * 16;
        }
        const bf16x8* w3p = (const bf16x8*)w3f;
        const char* ib = (const char*)interm;

        for (int rr = 0; rr < 2; ++rr) {
            const int ky = 2 * w + rr;
            const bf16x8* wrow = w3p + (ky * 9) * 128;
            const char* B0 = ib + abase[0] + ky * 1600;
            const char* B1 = ib + abase[1] + ky * 1600;
            const char* B2 = ib + abase[2] + ky * 1600;
#pragma unroll
            for (int kx = 0; kx < 9; ++kx) {
                bf16x8 a0  = wrow[kx * 128 + lane];
                bf16x8 a1v = wrow[kx * 128 + 64 + lane];
                bf16x8 b0 = *(const bf16x8*)(B0 + kx * 80);
                bf16x8 b1 = *(const bf16x8*)(B1 + kx * 80);
                bf16x8 b2 = *(const bf16x8*)(B2 + kx * 80);
                acc[0][0] = MFMA16(a0, b0, acc[0][0]);
                acc[1][0] = MFMA16(a1v, b0, acc[1][0]);
                acc[0][1] = MFMA16(a0, b1, acc[0][1]);
                acc[1][1] = MFMA16(a1v, b1, acc[1][1]);
                acc[0][2] = MFMA16(a0, b2, acc[0][2]);
                acc[1][2] = MFMA16(a1v, b2, acc[1][2]);
            }
        }
        // row 8 leftovers: w0:{0,1} w1:{2,3} w2:{4,5} w3:{6,7,8}
        {
            const bf16x8* wrow = w3p + 72 * 128;
            const char* B0 = ib + abase[0] + 12800;
            const char* B1 = ib + abase[1] + 12800;
            const char* B2 = ib + abase[2] + 12800;
            int kx0 = 2 * w;
            int nkx = (w == 3) ? 3 : 2;
#pragma unroll 3
            for (int q = 0; q < nkx; ++q) {
                int kx = kx0 + q;
                bf16x8 a0  = wrow[kx * 128 + lane];
                bf16x8 a1v = wrow[kx * 128 + 64 + lane];
                bf16x8 b0 = *(const bf16x8*)(B0 + kx * 80);
                bf16x8 b1 = *(const bf16x8*)(B1 + kx * 80);
                bf16x8 b2 = *(const bf16x8*)(B2 + kx * 80);
                acc[0][0] = MFMA16(a0, b0, acc[0][0]);
                acc[1][0] = MFMA16(a1v, b0, acc[1][0]);
                acc[0][1] = MFMA16(a0, b1, acc[0][1]);
                acc[1][1] = MFMA16(a1v, b1, acc[1][1]);
                acc[0][2] = MFMA16(a0, b2, acc[0][2]);
                acc[1][2] = MFMA16(a1v, b2, acc[1][2]);
            }
        }
    }
    __syncthreads();
    // ---- cross-wave reduction (f32x4 overlay on interm) ----
    f32x4* rp = (f32x4*)&interm[0];
    {
#pragma unroll
        for (int m = 0; m < 2; ++m)
#pragma unroll
            for (int nt = 0; nt < 3; ++nt)
                rp[(w * 6 + m * 3 + nt) * 64 + lane] = acc[m][nt];
    }
    __syncthreads();
    for (int idx = t; idx < 384; idx += 256) {
        int tile = idx >> 6, ls = idx & 63;
        f32x4 s = rp[tile * 64 + ls];
#pragma unroll
        for (int ww = 1; ww < 4; ++ww)
            s += rp[(ww * 6 + tile) * 64 + ls];
        int m = tile / 3, nt = tile - m * 3;
        int p2 = nt * 16 + (ls & 15);
        if (p2 < 36) {
            int gr = ls >> 4;
#pragma unroll
            for (int r = 0; r < 4; ++r) {
                int oc = m * 16 + gr * 4 + r;
                caps[(b * 8 + d) * 1152 + oc * 36 + p2] = fmaxf(s[r] + pb[oc], 0.f);
            }
        }
    }
}

// ---------------------------------------------------------------------------
// K2: routing, 576 threads. LDS diet for 3 blocks/CU (~50.3 KB):
//  - c buffer halved (two n-halves of 576 share an 11.7 KB buffer)
//  - stage-C partial scratch overlays the dead c buffer (barrier-separated)
//  - softmax results held packed bf16 (10 u32) to keep VGPR <= 64
// ---------------------------------------------------------------------------
#define USB 1160   // u_bf row stride (bf16)
#define CHS 584    // chalf row stride (bf16)

__global__ __launch_bounds__(576, 8) void k_route(
    const float* __restrict__ caps,  // [1024,8,1152]
    const unsigned short* __restrict__ Wbf,  // [1152,8,16] bf16
    const float* __restrict__ Wb,    // [1152,16]
    const float* __restrict__ ow,    // [10,10,16,1]
    const float* __restrict__ ob,    // [10]
    float* __restrict__ out)         // [1024,10]
{
    __shared__ __align__(16) unsigned short u_bf[16 * USB];   // 37,120 B
    __shared__ __align__(16) unsigned short chalf[10 * CHS];  // 11,680 B (+scratch overlay)
    __shared__ __align__(16) float vv[16 * 12];               //     768 B
    __shared__ float ss[160];                                 //     640 B
    __shared__ float red2[16];

    const int t = threadIdx.x;
    const int lane = t & 63, wv = t >> 6;
    const int g = lane >> 4, col = lane & 15;
    const int b = blockIdx.x;
    const int n0 = 2 * t;

    // ---- stage A: u[f][n] -> bf16 (W streamed as bf16) ----
    {
        const int nl = t >> 2, fq = t & 3;
        for (int base = 0; base < 1152; base += 144) {
            int n = base + nl;
            float cv[8];
#pragma unroll
            for (int e = 0; e < 8; ++e) cv[e] = caps[(b * 8 + e) * 1152 + n];
            float4 a4 = ((const float4*)(Wb + n * 16))[fq];
#pragma unroll
            for (int e = 0; e < 8; ++e) {
                uint2 wp = *(const uint2*)(&Wbf[n * 128 + e * 16 + fq * 4]);
                float w0 = __builtin_bit_cast(float, wp.x << 16);
                float w1 = __builtin_bit_cast(float, wp.x & 0xffff0000u);
                float w2 = __builtin_bit_cast(float, wp.y << 16);
                float w3 = __builtin_bit_cast(float, wp.y & 0xffff0000u);
                a4.x += cv[e] * w0; a4.y += cv[e] * w1;
                a4.z += cv[e] * w2; a4.w += cv[e] * w3;
            }
            u_bf[(fq * 4 + 0) * USB + n] = f2bf(a4.x);
            u_bf[(fq * 4 + 1) * USB + n] = f2bf(a4.y);
            u_bf[(fq * 4 + 2) * USB + n] = f2bf(a4.z);
            u_bf[(fq * 4 + 3) * USB + n] = f2bf(a4.w);
        }
    }
    float breg[2][10];
#pragma unroll
    for (int s = 0; s < 2; ++s)
#pragma unroll
        for (int jj = 0; jj < 10; ++jj) breg[s][jj] = 0.f;
    __syncthreads();

    const int jrow = (col < 10) ? col : 9;   // A-frag row clamp (broadcast on 10..15)
    const int hmine = (t >= 288);            // which n-half this thread's pair is in
    const int nh = 2 * t - 576 * hmine;      // local n within the half

    for (int iter = 0; iter < 3; ++iter) {
        // ---- softmax over j for n0,n0+1 -> packed bf16 pairs (registers) ----
        unsigned pk[10];
        {
            float cv2[2][10];
#pragma unroll
            for (int s = 0; s < 2; ++s) {
                float m = breg[s][0];
#pragma unroll
                for (int jj = 1; jj < 10; ++jj) m = fmaxf(m, breg[s][jj]);
                float sum = 0.f;
#pragma unroll
                for (int jj = 0; jj < 10; ++jj) { cv2[s][jj] = __expf(breg[s][jj] - m); sum += cv2[s][jj]; }
                float inv = 1.f / sum;
#pragma unroll
                for (int jj = 0; jj < 10; ++jj) cv2[s][jj] *= inv;
            }
#pragma unroll
            for (int jj = 0; jj < 10; ++jj)
                pk[jj] = cvtpk(cv2[0][jj], cv2[1][jj]);
        }

        // ---- stage B+C over two n-halves; sp accumulates in registers ----
        f32x4 sp = {0.f, 0.f, 0.f, 0.f};
#pragma unroll
        for (int h = 0; h < 2; ++h) {
            if (hmine == h) {
#pragma unroll
                for (int jj = 0; jj < 10; ++jj)
                    *(unsigned*)(&chalf[jj * CHS + nh]) = pk[jj];
            }
            __syncthreads();
#pragma unroll
            for (int mf = 0; mf < 2; ++mf) {
                int nk = wv * 64 + mf * 32 + g * 8;
                bf16x8 af = *(const bf16x8*)(&chalf[jrow * CHS + nk]);
                bf16x8 bf = *(const bf16x8*)(&u_bf[col * USB + h * 576 + nk]);
                sp = MFMA16(af, bf, sp);
            }
            __syncthreads();   // chalf reads done before overwrite
        }
        // ---- partials -> scratch (overlays chalf, 9x256 f32 = 9216 B) ----
        float* scratch = (float*)chalf;
        *(f32x4*)(&scratch[(wv * 64 + lane) * 4]) = sp;
        __syncthreads();
        // ---- reduce 9 wave-partials -> ss[j][f] ----
        if (t < 160) {
            int j = t >> 4, f = t & 15;
            int li = ((j >> 2) * 16 + f) * 4 + (j & 3);
            float s = 0.f;
#pragma unroll
            for (int ww = 0; ww < 9; ++ww) s += scratch[ww * 256 + li];
            ss[j * 16 + f] = s;
        }
        __syncthreads();
        // ---- squash -> vv[f][j] ----
        if (t < 16) {
            float sv[10], l2 = 0.f, l1 = 0.f;
#pragma unroll
            for (int jj = 0; jj < 10; ++jj) {
                sv[jj] = ss[jj * 16 + t];
                l2 += sv[jj] * sv[jj]; l1 += fabsf(sv[jj]);
            }
            l2 = sqrtf(l2);
            float scale = l2 / (1.f + l2) / l1;
#pragma unroll
            for (int jj = 0; jj < 10; ++jj) vv[t * 12 + jj] = sv[jj] * scale;
        }
        __syncthreads();
        // ---- stage E: breg += u^T v ----
        if (iter < 2) {
#pragma unroll
            for (int f = 0; f < 16; ++f) {
                unsigned pair = *(const unsigned*)(&u_bf[f * USB + n0]);
                float ux = __builtin_bit_cast(float, pair << 16);
                float uy = __builtin_bit_cast(float, pair & 0xffff0000u);
                f32x4 v0 = *(const f32x4*)(&vv[f * 12]);
                f32x4 v1 = *(const f32x4*)(&vv[f * 12 + 4]);
                float2 v2 = *(const float2*)(&vv[f * 12 + 8]);
                breg[0][0] += ux * v0.x; breg[1][0] += uy * v0.x;
                breg[0][1] += ux * v0.y; breg[1][1] += uy * v0.y;
                breg[0][2] += ux * v0.z; breg[1][2] += uy * v0.z;
                breg[0][3] += ux * v0.w; breg[1][3] += uy * v0.w;
                breg[0][4] += ux * v1.x; breg[1][4] += uy * v1.x;
                breg[0][5] += ux * v1.y; breg[1][5] += uy * v1.y;
                breg[0][6] += ux * v1.z; breg[1][6] += uy * v1.z;
                breg[0][7] += ux * v1.w; breg[1][7] += uy * v1.w;
                breg[0][8] += ux * v2.x; breg[1][8] += uy * v2.x;
                breg[0][9] += ux * v2.y; breg[1][9] += uy * v2.y;
            }
        }
        __syncthreads();
    }

    // ---- output head + softmax ----
    if (t < 10) {
        float l = ob[t];
#pragma unroll
        for (int i2 = 0; i2 < 10; ++i2)
#pragma unroll
            for (int ff = 0; ff < 16; ++ff)
                l += vv[ff * 12 + i2] * ow[t * 160 + i2 * 16 + ff];
        red2[t] = l;
    }
    __syncthreads();
    if (t == 0) {
        float m = -1e30f;
        for (int o = 0; o < 10; ++o) m = fmaxf(m, red2[o]);
        float sum = 0.f; float e[10];
        for (int o = 0; o < 10; ++o) { e[o] = __expf(red2[o] - m); sum += e[o]; }
        float inv = 1.f / sum;
        for (int o = 0; o < 10; ++o) out[b * 10 + o] = e[o] * inv;
    }
}

extern "C" void kernel_launch(void* const* d_in, const int* in_sizes, int n_in,
                              void* d_out, int out_size, void* d_ws, size_t ws_size,
                              hipStream_t stream) {
    const float* x     = (const float*)d_in[0];
    const float* c1w   = (const float*)d_in[1];
    const float* c1b   = (const float*)d_in[2];
    const float* pw    = (const float*)d_in[3];
    const float* pb    = (const float*)d_in[4];
    const float* digW  = (const float*)d_in[5];
    const float* digWb = (const float*)d_in[6];
    const float* outw  = (const float*)d_in[7];
    const float* outb  = (const float*)d_in[8];
    float* out = (float*)d_out;

    float* caps = (float*)d_ws;
    unsigned short* w1f = (unsigned short*)((char*)d_ws + CAPS_BYTES);
    unsigned short* w3f = w1f + A1F_ELEMS;
    unsigned short* wbf = w3f + W3F_ELEMS;

    k_prep<<<dim3(996), dim3(256), 0, stream>>>(c1w, pw, digW, w1f, w3f, wbf);
    k_conv<<<dim3(8192), dim3(256), 0, stream>>>(x, c1b, pb, w1f, w3f, caps);
    k_route<<<dim3(1024), dim3(576), 0, stream>>>(caps, wbf, digWb, outw, outb, out);
}